// Round 1
// 323.210 us; speedup vs baseline: 1.0176x; 1.0176x over previous
//
#include <hip/hip_runtime.h>
#include <math.h>

typedef __bf16 bf16x8 __attribute__((ext_vector_type(8)));
typedef float f32x4 __attribute__((ext_vector_type(4)));

// ---------------- weight conversion: fp32 -> bf16 frag-major in d_ws ----------
// Frag (kt,nt) = 32x16 block of B; lane L holds B[kt*32+(L>>4)*8+j][nt*16+(L&15)],
// j=0..7 -> one 16B chunk at L*16. Offsets (bf16 units): L1@0 (96x256, 48 frags),
// L2@24576 (256x128, 64), L3@57344 (128x64, 16), L4@65536 (64x128, 16; N 101->128 pad).
__global__ void conv_weights(const float* __restrict__ W1, const float* __restrict__ W2,
                             const float* __restrict__ W3, const float* __restrict__ W4,
                             __bf16* __restrict__ ws)
{
  const int f = blockIdx.x * 4 + (threadIdx.x >> 6);
  const int lane = threadIdx.x & 63;
  int f0, ntot, Ksrc, Nsrc, off;
  const float* W;
  if (f < 48)       { f0 = f;       ntot = 16; Ksrc = 80;  Nsrc = 256; W = W1; off = 0; }
  else if (f < 112) { f0 = f - 48;  ntot = 8;  Ksrc = 256; Nsrc = 128; W = W2; off = 24576; }
  else if (f < 128) { f0 = f - 112; ntot = 4;  Ksrc = 128; Nsrc = 64;  W = W3; off = 57344; }
  else              { f0 = f - 128; ntot = 8;  Ksrc = 64;  Nsrc = 101; W = W4; off = 65536; }
  const int kt = f0 / ntot, nt = f0 % ntot;
  const int q = lane >> 4, c = lane & 15;
  const int n = nt * 16 + c;
  bf16x8 v;
#pragma unroll
  for (int j = 0; j < 8; ++j) {
    const int k = kt * 32 + q * 8 + j;
    const float x = (k < Ksrc && n < Nsrc) ? W[k * Nsrc + n] : 0.f;
    v[j] = (__bf16)x;
  }
  ((bf16x8*)(ws + off))[f0 * 64 + lane] = v;
}

// ---------------- fused forward: zero-barrier + register burst prefetch -------
// Block = 4 waves x 16 rows. Each wave owns its rows end-to-end; B-fragments are
// loaded in explicit register bursts so MFMA never waits on a just-issued load.
// L2 layer uses depth-2 kt prefetch.
//
// LDS OVERLAY (this round): h1/h2/h3 all live at smw+0. Legal because every
// h2 write data-depends (via acc2 accumulation) on every A2 read of h1, and
// every h3 write depends on every A3 read of h2 — writes can never pass the
// reads they overwrite (plus per-wave DS is in-order). proj@576 overlaps h2's
// float range [576,1088): the proj-zero stores have NO data dep on A3 reads,
// so a compiler memory fence pins them (placed in L4, after A4 frag reads).
// Per-wave LDS: 2192 floats = 8768 B; block = 35072 B -> 4 blocks/CU
// (was 52480 B -> 3 blocks/CU). VGPR profile unchanged (~80) so occupancy
// should rise 12 -> 16 waves/CU.

__global__ __launch_bounds__(256, 3)
void sacq_wave(const float* __restrict__ obs,  const float* __restrict__ act,
               const float* __restrict__ rew,  const float* __restrict__ boot,
               const float* __restrict__ disc, const float* __restrict__ qsup,
               const float* __restrict__ b1, const float* __restrict__ g1, const float* __restrict__ be1,
               const float* __restrict__ b2, const float* __restrict__ g2, const float* __restrict__ be2,
               const float* __restrict__ b3, const float* __restrict__ g3, const float* __restrict__ be3,
               const float* __restrict__ b4,
               const __bf16* __restrict__ ws,
               float* __restrict__ out)
{
  __shared__ float sm[8768];
  const int t = threadIdx.x;
  const int wv = t >> 6, lane = t & 63;
  const int q = lane >> 4, c = lane & 15;
  float* smw = sm + wv * 2192;
  __bf16* h1 = (__bf16*)smw;             // [16][264]  floats [0,2112)
  __bf16* h2 = (__bf16*)smw;             // [16][136]  floats [0,1088)  (overlays h1)
  __bf16* h3 = (__bf16*)smw;             // [16][72]   floats [0,576)   (overlays h2)
  float*  proj = smw + 576;              // [16][101]  floats [576,2192)
  const int row0w = blockIdx.x * 64 + wv * 16;
  const bf16x8* wsf = (const bf16x8*)ws;

  // ================= Layer 1: x[16x80] @ W1 -> 256, LN+SiLU =================
  f32x4 acc1[16];
  {
    // ---- A fragments via float4 loads (rows are 240B/80B strided, 16B aligned)
    bf16x8 A1[3];
    const float4* ob4 = (const float4*)(obs + (size_t)(row0w + c) * 60);
    const float4* ac4 = (const float4*)(act + (size_t)(row0w + c) * 20);
#pragma unroll
    for (int kt = 0; kt < 3; ++kt) {
      const int k0 = kt * 32 + q * 8;
      float v[8];
      if (k0 < 56) {
        const float4 a = ob4[k0 / 4], b = ob4[k0 / 4 + 1];
        v[0]=a.x; v[1]=a.y; v[2]=a.z; v[3]=a.w; v[4]=b.x; v[5]=b.y; v[6]=b.z; v[7]=b.w;
      } else if (k0 == 56) {
        const float4 a = ob4[14], b = ac4[0];
        v[0]=a.x; v[1]=a.y; v[2]=a.z; v[3]=a.w; v[4]=b.x; v[5]=b.y; v[6]=b.z; v[7]=b.w;
      } else if (k0 < 80) {
        const float4 a = ac4[(k0 - 60) / 4], b = ac4[(k0 - 60) / 4 + 1];
        v[0]=a.x; v[1]=a.y; v[2]=a.z; v[3]=a.w; v[4]=b.x; v[5]=b.y; v[6]=b.z; v[7]=b.w;
      } else {
#pragma unroll
        for (int j = 0; j < 8; ++j) v[j] = 0.f;
      }
#pragma unroll
      for (int j = 0; j < 8; ++j) A1[kt][j] = (__bf16)v[j];
    }
#pragma unroll
    for (int nt = 0; nt < 16; ++nt) {
      const float bb = b1[nt * 16 + c];
      f32x4 vv = {bb, bb, bb, bb};
      acc1[nt] = vv;
    }
    // ---- 4 chunks of 4 ntiles; each chunk: burst 12 frag loads, then 12 MFMAs
#pragma unroll
    for (int ch = 0; ch < 4; ++ch) {
      bf16x8 Bb[3][4];
#pragma unroll
      for (int kt = 0; kt < 3; ++kt)
#pragma unroll
        for (int j = 0; j < 4; ++j)
          Bb[kt][j] = wsf[(kt * 16 + ch * 4 + j) * 64 + lane];
#pragma unroll
      for (int kt = 0; kt < 3; ++kt)
#pragma unroll
        for (int j = 0; j < 4; ++j)
          acc1[ch * 4 + j] = __builtin_amdgcn_mfma_f32_16x16x32_bf16(A1[kt], Bb[kt][j], acc1[ch * 4 + j], 0, 0, 0);
    }
    float mu[4], rs[4];
#pragma unroll
    for (int r = 0; r < 4; ++r) {
      float s = 0.f, s2 = 0.f;
#pragma unroll
      for (int nt = 0; nt < 16; ++nt) { const float v = acc1[nt][r]; s += v; s2 += v * v; }
      s += __shfl_xor(s, 1); s2 += __shfl_xor(s2, 1);
      s += __shfl_xor(s, 2); s2 += __shfl_xor(s2, 2);
      s += __shfl_xor(s, 4); s2 += __shfl_xor(s2, 4);
      s += __shfl_xor(s, 8); s2 += __shfl_xor(s2, 8);
      const float m = s * (1.f / 256.f);
      mu[r] = m;
      rs[r] = rsqrtf(s2 * (1.f / 256.f) - m * m + 1e-5f);
    }
#pragma unroll
    for (int nt = 0; nt < 16; ++nt) {
      const int col = nt * 16 + c;
      const float gg = g1[col], bb = be1[col];
#pragma unroll
      for (int r = 0; r < 4; ++r) {
        float v = (acc1[nt][r] - mu[r]) * rs[r] * gg + bb;
        v = v * __builtin_amdgcn_rcpf(1.f + __expf(-v));
        h1[(4 * q + r) * 264 + col] = (__bf16)v;
      }
    }
  }

  // ================= Layer 2: 256 -> 128, LN+SiLU (depth-2 kt prefetch) ======
  // h2 overlays h1: every h2 write depends on acc2 <- all 8 A2 reads of h1.
  {
    f32x4 acc2[8];
#pragma unroll
    for (int nt = 0; nt < 8; ++nt) {
      const float bb = b2[nt * 16 + c];
      f32x4 vv = {bb, bb, bb, bb};
      acc2[nt] = vv;
    }
    bf16x8 B2[3][8];
#pragma unroll
    for (int nt = 0; nt < 8; ++nt) B2[0][nt] = wsf[3072 + (0 * 8 + nt) * 64 + lane];
#pragma unroll
    for (int nt = 0; nt < 8; ++nt) B2[1][nt] = wsf[3072 + (1 * 8 + nt) * 64 + lane];
#pragma unroll
    for (int kt = 0; kt < 8; ++kt) {
      if (kt + 2 < 8) {
#pragma unroll
        for (int nt = 0; nt < 8; ++nt)
          B2[(kt + 2) % 3][nt] = wsf[3072 + ((kt + 2) * 8 + nt) * 64 + lane];
      }
      const bf16x8 A2 = *(const bf16x8*)(h1 + c * 264 + kt * 32 + q * 8);
#pragma unroll
      for (int nt = 0; nt < 8; ++nt)
        acc2[nt] = __builtin_amdgcn_mfma_f32_16x16x32_bf16(A2, B2[kt % 3][nt], acc2[nt], 0, 0, 0);
    }
    float mu[4], rs[4];
#pragma unroll
    for (int r = 0; r < 4; ++r) {
      float s = 0.f, s2 = 0.f;
#pragma unroll
      for (int nt = 0; nt < 8; ++nt) { const float v = acc2[nt][r]; s += v; s2 += v * v; }
      s += __shfl_xor(s, 1); s2 += __shfl_xor(s2, 1);
      s += __shfl_xor(s, 2); s2 += __shfl_xor(s2, 2);
      s += __shfl_xor(s, 4); s2 += __shfl_xor(s2, 4);
      s += __shfl_xor(s, 8); s2 += __shfl_xor(s2, 8);
      const float m = s * (1.f / 128.f);
      mu[r] = m;
      rs[r] = rsqrtf(s2 * (1.f / 128.f) - m * m + 1e-5f);
    }
#pragma unroll
    for (int nt = 0; nt < 8; ++nt) {
      const int col = nt * 16 + c;
      const float gg = g2[col], bb = be2[col];
#pragma unroll
      for (int r = 0; r < 4; ++r) {
        float v = (acc2[nt][r] - mu[r]) * rs[r] * gg + bb;
        v = v * __builtin_amdgcn_rcpf(1.f + __expf(-v));
        h2[(4 * q + r) * 136 + col] = (__bf16)v;
      }
    }
  }

  // ================= Layer 3: 128 -> 64, LN+SiLU (full 16-frag burst) ========
  // h3 overlays h2: h3 writes depend on acc3 <- all 4 A3 reads of h2.
  {
    bf16x8 B3[4][4];
#pragma unroll
    for (int kt = 0; kt < 4; ++kt)
#pragma unroll
      for (int nt = 0; nt < 4; ++nt)
        B3[kt][nt] = wsf[7168 + (kt * 4 + nt) * 64 + lane];
    f32x4 acc3[4];
#pragma unroll
    for (int nt = 0; nt < 4; ++nt) {
      const float bb = b3[nt * 16 + c];
      f32x4 vv = {bb, bb, bb, bb};
      acc3[nt] = vv;
    }
#pragma unroll
    for (int kt = 0; kt < 4; ++kt) {
      const bf16x8 A3 = *(const bf16x8*)(h2 + c * 136 + kt * 32 + q * 8);
#pragma unroll
      for (int nt = 0; nt < 4; ++nt)
        acc3[nt] = __builtin_amdgcn_mfma_f32_16x16x32_bf16(A3, B3[kt][nt], acc3[nt], 0, 0, 0);
    }
    float mu[4], rs[4];
#pragma unroll
    for (int r = 0; r < 4; ++r) {
      float s = 0.f, s2 = 0.f;
#pragma unroll
      for (int nt = 0; nt < 4; ++nt) { const float v = acc3[nt][r]; s += v; s2 += v * v; }
      s += __shfl_xor(s, 1); s2 += __shfl_xor(s2, 1);
      s += __shfl_xor(s, 2); s2 += __shfl_xor(s2, 2);
      s += __shfl_xor(s, 4); s2 += __shfl_xor(s2, 4);
      s += __shfl_xor(s, 8); s2 += __shfl_xor(s2, 8);
      const float m = s * (1.f / 64.f);
      mu[r] = m;
      rs[r] = rsqrtf(s2 * (1.f / 64.f) - m * m + 1e-5f);
    }
#pragma unroll
    for (int nt = 0; nt < 4; ++nt) {
      const int col = nt * 16 + c;
      const float gg = g3[col], bb = be3[col];
#pragma unroll
      for (int r = 0; r < 4; ++r) {
        float v = (acc3[nt][r] - mu[r]) * rs[r] * gg + bb;
        v = v * __builtin_amdgcn_rcpf(1.f + __expf(-v));
        h3[(4 * q + r) * 72 + col] = (__bf16)v;
      }
    }
  }

  // ================= Layer 4 (101 cols) + softmax + projection ===============
  {
    bf16x8 B4[2][7];
#pragma unroll
    for (int kt = 0; kt < 2; ++kt)
#pragma unroll
      for (int nt = 0; nt < 7; ++nt)
        B4[kt][nt] = wsf[8192 + (kt * 8 + nt) * 64 + lane];
    // A4 frag reads touch h3 floats [0,576) only — disjoint from proj [576,2192).
    bf16x8 A4f[2];
#pragma unroll
    for (int kt = 0; kt < 2; ++kt)
      A4f[kt] = *(const bf16x8*)(h3 + c * 72 + kt * 32 + q * 8);

    // Fence: proj-zero stores (float) have no data dep on the bf16 A3 reads
    // of the overlapping h2 region — pin them here (HW DS is in-order/wave).
    asm volatile("" ::: "memory");
    {
      f32x4 z = {0.f, 0.f, 0.f, 0.f};
      f32x4* p4 = (f32x4*)proj;
      for (int i = lane; i < 404; i += 64) p4[i] = z;
    }

    f32x4 a4[7];
#pragma unroll
    for (int nt = 0; nt < 7; ++nt) {
      const int col = nt * 16 + c;
      const float bb = (col < 101) ? b4[col] : 0.f;
      f32x4 vv = {bb, bb, bb, bb};
      a4[nt] = vv;
    }
#pragma unroll
    for (int kt = 0; kt < 2; ++kt) {
#pragma unroll
      for (int nt = 0; nt < 7; ++nt)
        a4[nt] = __builtin_amdgcn_mfma_f32_16x16x32_bf16(A4f[kt], B4[kt][nt], a4[nt], 0, 0, 0);
    }

    // softmax over 101 atoms per row, fully in-register
    float mx4[4] = {-3.4e38f, -3.4e38f, -3.4e38f, -3.4e38f};
#pragma unroll
    for (int nt = 0; nt < 7; ++nt) {
      const bool ok = (nt < 6) | (c < 5);
#pragma unroll
      for (int r = 0; r < 4; ++r)
        if (ok) mx4[r] = fmaxf(mx4[r], a4[nt][r]);
    }
#pragma unroll
    for (int r = 0; r < 4; ++r) {
      mx4[r] = fmaxf(mx4[r], __shfl_xor(mx4[r], 1));
      mx4[r] = fmaxf(mx4[r], __shfl_xor(mx4[r], 2));
      mx4[r] = fmaxf(mx4[r], __shfl_xor(mx4[r], 4));
      mx4[r] = fmaxf(mx4[r], __shfl_xor(mx4[r], 8));
    }
    float sm4[4] = {0.f, 0.f, 0.f, 0.f};
#pragma unroll
    for (int nt = 0; nt < 7; ++nt) {
      const bool ok = (nt < 6) | (c < 5);
#pragma unroll
      for (int r = 0; r < 4; ++r) {
        const float e = ok ? __expf(a4[nt][r] - mx4[r]) : 0.f;
        a4[nt][r] = e;
        sm4[r] += e;
      }
    }
    float inv4[4];
#pragma unroll
    for (int r = 0; r < 4; ++r) {
      float s = sm4[r];
      s += __shfl_xor(s, 1);
      s += __shfl_xor(s, 2);
      s += __shfl_xor(s, 4);
      s += __shfl_xor(s, 8);
      inv4[r] = __builtin_amdgcn_rcpf(s);
    }

    float rwv[4], bdv[4];
#pragma unroll
    for (int r = 0; r < 4; ++r) {
      const int gr = row0w + 4 * q + r;
      rwv[r] = rew[gr];
      bdv[r] = boot[gr] * disc[gr];
    }

    // categorical projection: wave-private LDS atomics
#pragma unroll
    for (int nt = 0; nt < 7; ++nt) {
      const int col = nt * 16 + c;
      if ((nt < 6) | (c < 5)) {
        const float qsv = qsup[col];
#pragma unroll
        for (int r = 0; r < 4; ++r) {
          const float p = a4[nt][r] * inv4[r];
          float tz = rwv[r] + bdv[r] * qsv;
          tz = fminf(fmaxf(tz, -10.f), 10.f);
          const float b_ = (tz + 10.f) * 5.f;
          const float fl = floorf(b_), cl = ceilf(b_);
          int li = (int)fl, ui = (int)cl;
          if (ui == li) { if (li > 0) --li; else ++ui; }
          const int rb = (4 * q + r) * 101;
          atomicAdd(&proj[rb + li], p * ((float)ui - b_));
          atomicAdd(&proj[rb + ui], p * (b_ - (float)li));
        }
      }
    }
  }

  // ---- coalesced float4 writeout of this wave's 16x101 block
  {
    const f32x4* p4 = (const f32x4*)proj;
    f32x4* o4 = (f32x4*)(out + (size_t)row0w * 101);
    for (int i = lane; i < 404; i += 64) o4[i] = p4[i];
  }
}

extern "C" void kernel_launch(void* const* d_in, const int* in_sizes, int n_in,
                              void* d_out, int out_size, void* d_ws, size_t ws_size,
                              hipStream_t stream)
{
  const int B = in_sizes[2];  // rewards: B elements
  __bf16* ws = (__bf16*)d_ws; // 147456 B used

  conv_weights<<<dim3(36), dim3(256), 0, stream>>>(
      (const float*)d_in[6], (const float*)d_in[10], (const float*)d_in[14],
      (const float*)d_in[18], ws);

  sacq_wave<<<dim3(B / 64), dim3(256), 0, stream>>>(
      (const float*)d_in[0],  (const float*)d_in[1],  (const float*)d_in[2],
      (const float*)d_in[3],  (const float*)d_in[4],  (const float*)d_in[5],
      (const float*)d_in[7],  (const float*)d_in[8],  (const float*)d_in[9],
      (const float*)d_in[11], (const float*)d_in[12], (const float*)d_in[13],
      (const float*)d_in[15], (const float*)d_in[16], (const float*)d_in[17],
      (const float*)d_in[19], ws, (float*)d_out);
}